// Round 5
// baseline (41.441 us; speedup 1.0000x reference)
//
#include <hip/hip_runtime.h>
#include <hip/hip_bf16.h>
#include <stdint.h>

// Chamfer distance, B=2, N=M=8192, fp32 3-D points — MFMA, two transposed passes.
//
// d2[n][m] = |p_n|^2 + |g_m|^2 - 2 p_n.g_m inside v_mfma_f32_32x32x16_bf16 via
// split-bf16 (hi+lo), K=16 (encoding + A/B/C layouts verified R3/R4: absmax 0.0):
//   A_k: [-2hx,-2hy,-2hz, -2hx,-2hy,-2hz, -2lx,-2ly,-2lz, -2lx,-2ly,-2lz, h2,l2,1,1]
//   B_k: [ hx, hy, hz,  lx, ly, lz,  hx, hy, hz,  lx, ly, lz,  1,1, h2,l2]
// Two passes (dir 0/1) with A/B roles swapped; only row-mins needed, folded
// in-register: 8 v_min3 per MFMA = the structural VALU floor (~1.7us).
//
// R5 vs R4 (30.5us): the mfma kernel was ~20us vs a ~5us model — per-wave
// global B-fetch (268MB of L2 reads behind a 6-deep ring) + runtime ring
// address math. Now: B staged in LDS once per block (4 waves share, double
// buffered, 64MB global total), B stored as two k-half PLANES so stage loads,
// LDS writes and ds_read_b128 are all lane-contiguous (minimal bank pattern);
// A-encode inlined (prep packs B only); inner loop fully unrolled.

typedef __attribute__((ext_vector_type(8))) short short8v;
typedef __attribute__((ext_vector_type(16))) float f32x16;

#define NP 8192
#define NCHUNK 4
#define CHUNKCOLS 2048
#define NSTEP 128
#define NSTEPS (CHUNKCOLS / NSTEP)   // 16
#define SCALE 0.390625f              // 80^2 / (2 * 8192)

// ws byte offsets
#define OFF_ROW 0u         // float[4 db][4 chunk][8192]      row-min partials (512 KB)
#define OFF_B   1048576u   // uint4[4 db][2 half][8192]       B k-half planes (4 MB)

__device__ inline uint32_t f2u(float f){ union{float f;uint32_t u;}c; c.f=f; return c.u; }
__device__ inline float u2f(uint32_t u){ union{float f;uint32_t u;}c; c.u=u; return c.f; }
__device__ inline uint16_t bfr(float f){ uint32_t u=f2u(f); return (uint16_t)((u + 0x7FFFu + ((u>>16)&1u))>>16); }
__device__ inline float bff(uint16_t s){ return u2f(((uint32_t)s)<<16); }
__device__ inline float min3f(float a,float b,float c){ return fminf(fminf(a,b),c); }

// ---------------- prep: pack B planes only ----------------
__global__ __launch_bounds__(256) void prep_kernel(
    const float* __restrict__ pred, const float* __restrict__ gt,
    float* __restrict__ out, uint8_t* __restrict__ ws) {
  const int tid = blockIdx.x*256 + (int)threadIdx.x;   // 0..65535
  if (tid == 0) out[0] = 0.0f;
  const int col  = tid & 8191;
  const int half = (tid >> 13) & 1;
  const int db   = tid >> 14;          // dir*2 + b
  const int dir = db >> 1, b = db & 1;

  // B side: dir0 -> gt, dir1 -> pred
  const float* src = (dir == 0 ? gt : pred) + ((size_t)b*NP + col)*3;
  const float x = src[0], y = src[1], z = src[2];

  const uint16_t hx=bfr(x), hy=bfr(y), hz=bfr(z);
  const uint16_t lx=bfr(x-bff(hx)), ly=bfr(y-bff(hy)), lz=bfr(z-bff(hz));
  const float s2 = fmaf(x,x,fmaf(y,y,z*z));
  const uint16_t h2=bfr(s2), l2=bfr(s2-bff(h2));
  union{ ushort u[16]; uint4 v[2]; } B;
  B.u[0]=hx; B.u[1]=hy; B.u[2]=hz; B.u[3]=lx; B.u[4]=ly; B.u[5]=lz;
  B.u[6]=hx; B.u[7]=hy; B.u[8]=hz; B.u[9]=lx; B.u[10]=ly; B.u[11]=lz;
  B.u[12]=0x3F80; B.u[13]=0x3F80; B.u[14]=h2; B.u[15]=l2;

  uint4* BP = (uint4*)(ws + OFF_B);
  BP[(size_t)tid] = half ? B.v[1] : B.v[0];   // [(db*2+half)*NP + col]
}

// ---------------- main MFMA kernel ----------------
__global__ __launch_bounds__(256) void chamfer_mfma_kernel(
    const float* __restrict__ pred, const float* __restrict__ gt,
    uint8_t* __restrict__ ws) {
  const int wave = threadIdx.x >> 6, lane = threadIdx.x & 63;
  const int half = lane >> 5, l31 = lane & 31;
  const int stripe = blockIdx.x*4 + wave;   // row stripe of 32
  const int chunk  = blockIdx.y;
  const int db     = blockIdx.z;            // dir*2 + b
  const int dir = db >> 1, b = db & 1;

  // ---- inline A-encode (one-time): A side: dir0 -> pred, dir1 -> gt
  const int arow = stripe*32 + l31;
  const float* ap = (dir == 0 ? pred : gt) + ((size_t)b*NP + arow)*3;
  short8v afrag;
  {
    const float x = ap[0], y = ap[1], z = ap[2];
    const uint16_t hx=bfr(x), hy=bfr(y), hz=bfr(z);
    const uint16_t lx=bfr(x-bff(hx)), ly=bfr(y-bff(hy)), lz=bfr(z-bff(hz));
    const float s2 = fmaf(x,x,fmaf(y,y,z*z));
    const uint16_t h2=bfr(s2), l2=bfr(s2-bff(h2));
    const uint16_t nhx=bfr(-2.f*bff(hx)), nhy=bfr(-2.f*bff(hy)), nhz=bfr(-2.f*bff(hz));
    const uint16_t nlx=bfr(-2.f*bff(lx)), nly=bfr(-2.f*bff(ly)), nlz=bfr(-2.f*bff(lz));
    union{ ushort u[16]; short8v s8[2]; } A;
    A.u[0]=nhx; A.u[1]=nhy; A.u[2]=nhz; A.u[3]=nhx; A.u[4]=nhy; A.u[5]=nhz;
    A.u[6]=nlx; A.u[7]=nly; A.u[8]=nlz; A.u[9]=nlx; A.u[10]=nly; A.u[11]=nlz;
    A.u[12]=h2; A.u[13]=l2; A.u[14]=0x3F80; A.u[15]=0x3F80;
    afrag = half ? A.s8[1] : A.s8[0];
  }

  // ---- B staging: [buf][half][col] uint4, double buffered (8 KB)
  __shared__ uint4 lds[2][2][NSTEP];
  const uint4* BP = (const uint4*)(ws + OFF_B) + (size_t)db*2*NP
                    + (size_t)chunk*CHUNKCOLS;
  const int st_half = threadIdx.x >> 7;       // 0..1
  const int st_col  = threadIdx.x & 127;

  float rowmin[16];
#pragma unroll
  for (int i=0;i<16;++i) rowmin[i] = 3.4e38f;
  const f32x16 zero = {};

  // prologue stage
  lds[0][st_half][st_col] = BP[(size_t)st_half*NP + st_col];
  __syncthreads();

  int buf = 0;
  for (int s = 0; s < NSTEPS; ++s) {
    if (s + 1 < NSTEPS) {
      lds[buf^1][st_half][st_col] =
          BP[(size_t)st_half*NP + (s+1)*NSTEP + st_col];
    }
    const uint4* lrow = &lds[buf][half][0];
#pragma unroll
    for (int pr = 0; pr < 2; ++pr) {
      const short8v b0 = *(const short8v*)&lrow[pr*64 + l31];
      const short8v b1 = *(const short8v*)&lrow[pr*64 + 32 + l31];
      const f32x16 a0 = __builtin_amdgcn_mfma_f32_32x32x16_bf16(afrag, b0, zero, 0,0,0);
      const f32x16 a1 = __builtin_amdgcn_mfma_f32_32x32x16_bf16(afrag, b1, zero, 0,0,0);
#pragma unroll
      for (int i=0;i<16;++i) rowmin[i] = min3f(rowmin[i], a0[i], a1[i]);
    }
    __syncthreads();
    buf ^= 1;
  }

  // ---- row-min across the 32 cols held per half-wave
#pragma unroll
  for (int i=0;i<16;++i) {
    float v = rowmin[i];
    v = fminf(v, __shfl_xor(v, 1));
    v = fminf(v, __shfl_xor(v, 2));
    v = fminf(v, __shfl_xor(v, 4));
    v = fminf(v, __shfl_xor(v, 8));
    v = fminf(v, __shfl_xor(v, 16));
    rowmin[i] = v;
  }
  if (l31 == 0) {
    // C/D map (verified): row = (i&3) + 8*(i>>2) + 4*half
    float* wr = (float*)(ws + OFF_ROW) + ((size_t)db*NCHUNK + chunk)*NP
                + stripe*32 + half*4;
#pragma unroll
    for (int i=0;i<16;++i) wr[(i&3) + 8*(i>>2)] = rowmin[i];
  }
}

// ---------------- final reduce ----------------
__global__ __launch_bounds__(256) void reduce_kernel(
    const uint8_t* __restrict__ ws, float* __restrict__ out) {
  const float* WROW = (const float*)(ws + OFF_ROW);
  const int tid = blockIdx.x*256 + (int)threadIdx.x;  // 0..32767
  const int db = tid >> 13, q = tid & 8191;

  const float* pr = WROW + (size_t)db*NCHUNK*NP + q;
  const float m0 = fminf(pr[0], pr[NP]);
  const float m1 = fminf(pr[2*NP], pr[3*NP]);
  float sum = fmaxf(fminf(m0, m1), 0.0f);  // clamp == ref's maximum(d2,0)

#pragma unroll
  for (int off=32; off>0; off>>=1) sum += __shfl_down(sum, off);
  __shared__ float red[4];
  if ((threadIdx.x & 63) == 0) red[threadIdx.x >> 6] = sum;
  __syncthreads();
  if (threadIdx.x == 0) atomicAdd(out, (red[0]+red[1]+red[2]+red[3]) * SCALE);
}

extern "C" void kernel_launch(void* const* d_in, const int* in_sizes, int n_in,
                              void* d_out, int out_size, void* d_ws, size_t ws_size,
                              hipStream_t stream) {
  const float* pred = (const float*)d_in[0];
  const float* gt = (const float*)d_in[1];
  float* out = (float*)d_out;
  uint8_t* ws = (uint8_t*)d_ws;

  prep_kernel<<<256, 256, 0, stream>>>(pred, gt, out, ws);
  chamfer_mfma_kernel<<<dim3(NP/128, NCHUNK, 4), 256, 0, stream>>>(pred, gt, ws);
  reduce_kernel<<<128, 256, 0, stream>>>(ws, out);
}